// Round 5
// baseline (229.548 us; speedup 1.0000x reference)
//
#include <hip/hip_runtime.h>
#include <hip/hip_bf16.h>
#include <stdint.h>
#include <type_traits>

#define BS 4
#define LEN 5440
#define ROWS (BS * LEN)     // 21760 = 340 * 64

typedef __bf16 bf16;
typedef __bf16 bf16x2 __attribute__((ext_vector_type(2)));
typedef __bf16 bf16x4 __attribute__((ext_vector_type(4)));
typedef __bf16 bf16x8 __attribute__((ext_vector_type(8)));
typedef float f32x4 __attribute__((ext_vector_type(4)));

// ---------------------------------------------------------------------------
// Weight prep: LDS 64x64 tile transpose, coalesced read AND write.
// 57 blocks: 0-15 vproj->bt_v, 16-31 off->bt_oa[0:256), 32-39 attn->bt_oa[256:384),
// 40-55 out->bt_out, 56 bias concat.
// ---------------------------------------------------------------------------
__global__ __launch_bounds__(256) void prep_weights(
    const float* __restrict__ vproj_w, const float* __restrict__ off_w,
    const float* __restrict__ attn_w, const float* __restrict__ out_w,
    const float* __restrict__ off_b, const float* __restrict__ attn_b,
    bf16* __restrict__ bt_v, bf16* __restrict__ bt_oa, bf16* __restrict__ bt_out,
    float* __restrict__ bias_oa)
{
    const int blk = blockIdx.x;
    const int t = threadIdx.x;
    if (blk == 56) {
        bias_oa[t] = off_b[t];
        if (t < 128) bias_oa[256 + t] = attn_b[t];
        return;
    }
    const float* W; bf16* BT; int N, tn, tk;
    if (blk < 16)      { W = vproj_w; BT = bt_v;            N = 256; tk = blk >> 2;        tn = blk & 3; }
    else if (blk < 32) { W = off_w;   BT = bt_oa;           N = 256; tk = (blk - 16) >> 2; tn = (blk - 16) & 3; }
    else if (blk < 40) { W = attn_w;  BT = bt_oa + 256*256; N = 128; tk = (blk - 32) >> 1; tn = (blk - 32) & 1; }
    else               { W = out_w;   BT = bt_out;          N = 256; tk = (blk - 40) >> 2; tn = (blk - 40) & 3; }
    const int k0 = tk * 64, n0 = tn * 64;

    __shared__ float sT[64][65];
    const int r = t >> 2;             // 0..63
    const int cs = (t & 3) * 16;      // col segment
    const float* src = W + (size_t)(k0 + r) * N + n0 + cs;
#pragma unroll
    for (int i = 0; i < 4; ++i) {
        float4 a = *(const float4*)(src + i * 4);
        sT[r][cs + i * 4 + 0] = a.x; sT[r][cs + i * 4 + 1] = a.y;
        sT[r][cs + i * 4 + 2] = a.z; sT[r][cs + i * 4 + 3] = a.w;
    }
    __syncthreads();
    // output: BT[n0 + r][k0 + cs .. +15] = sT[cs+i][r]
    bf16x8 o0, o1;
#pragma unroll
    for (int i = 0; i < 8; ++i) o0[i] = (bf16)sT[cs + i][r];
#pragma unroll
    for (int i = 0; i < 8; ++i) o1[i] = (bf16)sT[cs + 8 + i][r];
    bf16* dst = BT + (size_t)(n0 + r) * 256 + k0 + cs;
    *(bf16x8*)dst = o0;
    *(bf16x8*)(dst + 8) = o1;
}

// ---------------------------------------------------------------------------
// Zero-LDS, zero-barrier MFMA GEMM body.
// Block 256 thr = 4 waves; tile 64 rows x 128 cols. Wave w: cols w*32..+31.
// B fragments (2 ntiles x 8 ki x 16B) loaded once from global BT (L2-hot,
// already fragment-layout) into 64 VGPRs. A streamed per mtile from global.
// ---------------------------------------------------------------------------
template <typename AT, typename OutT>
__device__ __forceinline__ void gemm_body(
    const AT* __restrict__ A, const bf16* __restrict__ BT,
    const float* __restrict__ bias, OutT* __restrict__ C,
    int N, int n0, int m0, int tid)
{
    const int wave = tid >> 6;
    const int lane = tid & 63;
    const int l15  = lane & 15;
    const int quad = lane >> 4;
    const int ncol = n0 + wave * 32;

    bf16x8 bfr[2][8];
#pragma unroll
    for (int nt = 0; nt < 2; ++nt) {
        const bf16* bp = BT + (size_t)(ncol + nt * 16 + l15) * 256 + quad * 8;
#pragma unroll
        for (int ki = 0; ki < 8; ++ki)
            bfr[nt][ki] = *(const bf16x8*)(bp + ki * 32);
    }

    f32x4 acc[4][2] = {};

#pragma unroll
    for (int mt = 0; mt < 4; ++mt) {
        const AT* arow = A + (size_t)(m0 + mt * 16 + l15) * 256 + quad * 8;
        bf16x8 afr[8];
#pragma unroll
        for (int ki = 0; ki < 8; ++ki) {
            if constexpr (std::is_same_v<AT, float>) {
                float4 f0 = *(const float4*)(arow + ki * 32);
                float4 f1 = *(const float4*)(arow + ki * 32 + 4);
                afr[ki] = bf16x8{(bf16)f0.x, (bf16)f0.y, (bf16)f0.z, (bf16)f0.w,
                                 (bf16)f1.x, (bf16)f1.y, (bf16)f1.z, (bf16)f1.w};
            } else {
                afr[ki] = *(const bf16x8*)(arow + ki * 32);
            }
        }
#pragma unroll
        for (int ki = 0; ki < 8; ++ki) {
#pragma unroll
            for (int nt = 0; nt < 2; ++nt)
                acc[mt][nt] = __builtin_amdgcn_mfma_f32_16x16x32_bf16(
                    afr[ki], bfr[nt][ki], acc[mt][nt], 0, 0, 0);
        }
    }

#pragma unroll
    for (int mt = 0; mt < 4; ++mt) {
#pragma unroll
        for (int nt = 0; nt < 2; ++nt) {
            const int col = ncol + nt * 16 + l15;
            const float bv = bias[col];
#pragma unroll
            for (int r = 0; r < 4; ++r) {
                const int rr = m0 + mt * 16 + (quad << 2) + r;
                float val = acc[mt][nt][r] + bv;
                if constexpr (std::is_same_v<OutT, float>)
                    C[(uint32_t)(rr * N + col)] = val;
                else
                    C[(uint32_t)(rr * N + col)] = (bf16)val;
            }
        }
    }
}

// Front GEMMs fused, XCD-swizzled. grid = 1720 (8 XCD x 215 steps).
// XCD x owns m-blocks == x (mod 8); per m it sweeps the 5 n-blocks
// consecutively so the A-stripe + BT stay in that XCD's L2.
// n-block 0,1 -> value@vproj (N=256); 2,3,4 -> query@[off|attn] (N=384).
__global__ __launch_bounds__(256) void gemm_front(
    const float* __restrict__ value, const float* __restrict__ query,
    const bf16* __restrict__ bt_v, const bf16* __restrict__ bt_oa,
    const float* __restrict__ bias_v, const float* __restrict__ bias_oa,
    bf16* __restrict__ v_bf, bf16* __restrict__ oa_bf)
{
    const int g = blockIdx.x;
    const int x = g & 7;
    const int s = g >> 3;
    const int m_idx = (s / 5) * 8 + x;
    if (m_idx >= 340) return;
    const int nb = s % 5;
    const int m0 = m_idx * 64;
    if (nb < 2)
        gemm_body<float, bf16>(value, bt_v, bias_v, v_bf, 256, nb * 128, m0, threadIdx.x);
    else
        gemm_body<float, bf16>(query, bt_oa, bias_oa, oa_bf, 384, (nb - 2) * 128, m0, threadIdx.x);
}

// Back GEMM, XCD-swizzled. grid = 688 (8 x 86).
__global__ __launch_bounds__(256) void gemm_back(
    const bf16* __restrict__ pre, const bf16* __restrict__ bt_out,
    const float* __restrict__ out_b, float* __restrict__ out)
{
    const int g = blockIdx.x;
    const int x = g & 7;
    const int s = g >> 3;
    const int m_idx = (s >> 1) * 8 + x;
    if (m_idx >= 340) return;
    gemm_body<bf16, float>(pre, bt_out, out_b, out, 256, (s & 1) * 128,
                           m_idx * 64, threadIdx.x);
}

// ---------------------------------------------------------------------------
// Fused softmax + multi-scale bilinear sampling (unchanged from round 4).
// ---------------------------------------------------------------------------
__global__ __launch_bounds__(256) void msda_sample(
    const bf16* __restrict__ v,        // [BS][LEN][256]
    const float* __restrict__ ref_pts, // [BS][LEN][4][2]
    const bf16* __restrict__ oa,       // [BS][LEN][384]
    bf16* __restrict__ pre)            // [BS][LEN][256]
{
    const int ib = blockIdx.x;
    const int b  = (ib & 7) >> 1;
    const int qg = ((ib >> 3) << 1) + (ib & 1);
    const int q0 = qg * 4;
    const int tid = threadIdx.x;

    __shared__ float  s_ref[32];
    __shared__ float  s_wn[512];
    __shared__ float4 s_tw[544];    // [32 (q,h)][16 pt] stride 17
    __shared__ int4   s_to[544];

    const uint32_t rowbase = (uint32_t)(b * LEN + q0);

    if (tid < 32) {
        s_ref[tid] = ref_pts[rowbase * 8 + tid];
        const int qi = tid >> 3, h = tid & 7;
        const bf16* ap = oa + (rowbase + qi) * 384 + 256 + h * 16;
        bf16x8 l0 = *(const bf16x8*)ap;
        bf16x8 l1 = *(const bf16x8*)(ap + 8);
        float lg[16];
#pragma unroll
        for (int i = 0; i < 8; ++i) { lg[i] = (float)l0[i]; lg[8 + i] = (float)l1[i]; }
        float m = -1e30f;
#pragma unroll
        for (int i = 0; i < 16; ++i) m = fmaxf(m, lg[i]);
        float s = 0.f;
#pragma unroll
        for (int i = 0; i < 16; ++i) { lg[i] = __expf(lg[i] - m); s += lg[i]; }
        const float inv = 1.f / s;
#pragma unroll
        for (int i = 0; i < 16; ++i) s_wn[qi * 128 + h * 16 + i] = lg[i] * inv;
    }
    __syncthreads();

#pragma unroll
    for (int it = 0; it < 2; ++it) {
        const int item = tid + it * 256;
        const int g  = item >> 4;
        const int qi = item >> 7;
        const int h  = (item >> 4) & 7;
        const int pt = item & 15;
        const int l  = pt >> 2;
        const int iw = 64 >> l;
        const int st = (l == 0) ? 0 : ((l == 1) ? 4096 : ((l == 2) ? 5120 : 5376));
        const float fiw = (float)iw;

        bf16x2 ob = *(const bf16x2*)(oa + (rowbase + qi) * 384 + (h * 16 + pt) * 2);
        const float x = s_ref[qi * 8 + l * 2 + 0] * fiw - 0.5f + (float)ob[0];
        const float y = s_ref[qi * 8 + l * 2 + 1] * fiw - 0.5f + (float)ob[1];
        const float x0f = floorf(x), y0f = floorf(y);
        const int x0 = (int)x0f, y0 = (int)y0f;
        const int x1 = x0 + 1, y1 = y0 + 1;
        const float fx = x - x0f, fy = y - y0f;
        const float wa = s_wn[qi * 128 + h * 16 + pt];
        const float w00 = (1.f - fx) * (1.f - fy) * wa;
        const float w10 = (1.f - fx) * fy * wa;
        const float w01 = fx * (1.f - fy) * wa;
        const float w11 = fx * fy * wa;
        const bool xi0 = (x0 >= 0) & (x0 < iw);
        const bool xi1 = (x1 >= 0) & (x1 < iw);
        const bool yi0 = (y0 >= 0) & (y0 < iw);
        const bool yi1 = (y1 >= 0) & (y1 < iw);
        const int xc0 = min(max(x0, 0), iw - 1), xc1 = min(max(x1, 0), iw - 1);
        const int yc0 = min(max(y0, 0), iw - 1), yc1 = min(max(y1, 0), iw - 1);
        const int hb = h * 64;
        s_tw[g * 17 + pt] = make_float4((xi0 & yi0) ? w00 : 0.f, (xi0 & yi1) ? w10 : 0.f,
                                        (xi1 & yi0) ? w01 : 0.f, (xi1 & yi1) ? w11 : 0.f);
        s_to[g * 17 + pt] = make_int4(((st + yc0 * iw + xc0) << 9) + hb,
                                      ((st + yc1 * iw + xc0) << 9) + hb,
                                      ((st + yc0 * iw + xc1) << 9) + hb,
                                      ((st + yc1 * iw + xc1) << 9) + hb);
    }
    __syncthreads();

    const int qi = tid >> 6;
    const int u  = tid & 63;
    const int h  = u >> 3;
    const int c8 = u & 7;
    const char* vbc = (const char*)(v + (uint32_t)b * (LEN * 256));
    const uint32_t lb = (uint32_t)(c8 * 8);
    const int base = (qi * 8 + h) * 17;

    float a0 = 0.f, a1 = 0.f, a2 = 0.f, a3 = 0.f;
#pragma unroll
    for (int pt = 0; pt < 16; ++pt) {
        const float4 w4 = s_tw[base + pt];
        const int4   o4 = s_to[base + pt];
#define TAP(OFF, W) { \
        uint2 d = *(const uint2*)(vbc + ((uint32_t)(OFF) + lb)); \
        a0 = fmaf(__uint_as_float(d.x << 16),          (W), a0); \
        a1 = fmaf(__uint_as_float(d.x & 0xffff0000u),  (W), a1); \
        a2 = fmaf(__uint_as_float(d.y << 16),          (W), a2); \
        a3 = fmaf(__uint_as_float(d.y & 0xffff0000u),  (W), a3); }
        TAP(o4.x, w4.x)
        TAP(o4.y, w4.y)
        TAP(o4.z, w4.z)
        TAP(o4.w, w4.w)
#undef TAP
    }

    bf16x4 o = {(bf16)a0, (bf16)a1, (bf16)a2, (bf16)a3};
    *(bf16x4*)(pre + (rowbase + qi) * 256 + h * 32 + c8 * 4) = o;
}

// ---------------------------------------------------------------------------
// Launch: 4 dispatches
// ---------------------------------------------------------------------------
extern "C" void kernel_launch(void* const* d_in, const int* in_sizes, int n_in,
                              void* d_out, int out_size, void* d_ws, size_t ws_size,
                              hipStream_t stream) {
    const float* query   = (const float*)d_in[0];
    const float* ref_pts = (const float*)d_in[1];
    const float* value   = (const float*)d_in[2];
    const float* vproj_w = (const float*)d_in[5];
    const float* vproj_b = (const float*)d_in[6];
    const float* off_w   = (const float*)d_in[7];
    const float* off_b   = (const float*)d_in[8];
    const float* attn_w  = (const float*)d_in[9];
    const float* attn_b  = (const float*)d_in[10];
    const float* out_w   = (const float*)d_in[11];
    const float* out_b   = (const float*)d_in[12];
    float* out = (float*)d_out;

    bf16* ws = (bf16*)d_ws;
    bf16* v_bf    = ws;                                // ROWS*256
    bf16* oa_bf   = v_bf   + (size_t)ROWS * 256;       // ROWS*384
    bf16* pre_bf  = oa_bf  + (size_t)ROWS * 384;       // ROWS*256
    bf16* bt_v    = pre_bf + (size_t)ROWS * 256;       // 256*256
    bf16* bt_oa   = bt_v   + 256 * 256;                // 384*256
    bf16* bt_out  = bt_oa  + 384 * 256;                // 256*256
    float* bias_oa = (float*)(bt_out + 256 * 256);     // 384 f32

    dim3 blk(256);

    prep_weights<<<dim3(57), blk, 0, stream>>>(vproj_w, off_w, attn_w, out_w,
                                               off_b, attn_b, bt_v, bt_oa, bt_out, bias_oa);

    gemm_front<<<dim3(1720), blk, 0, stream>>>(value, query, bt_v, bt_oa,
                                               vproj_b, bias_oa, v_bf, oa_bf);

    msda_sample<<<dim3(5440), blk, 0, stream>>>(v_bf, ref_pts, oa_bf, pre_bf);

    gemm_back<<<dim3(688), blk, 0, stream>>>(pre_bf, bt_out, out_b, out);
}

// Round 6
// 175.866 us; speedup vs baseline: 1.3052x; 1.3052x over previous
//
#include <hip/hip_runtime.h>
#include <hip/hip_bf16.h>
#include <stdint.h>
#include <type_traits>

#define BS 4
#define LEN 5440
#define ROWS (BS * LEN)     // 21760 = 340 * 64

typedef __bf16 bf16;
typedef __bf16 bf16x2 __attribute__((ext_vector_type(2)));
typedef __bf16 bf16x4 __attribute__((ext_vector_type(4)));
typedef __bf16 bf16x8 __attribute__((ext_vector_type(8)));
typedef float f32x4 __attribute__((ext_vector_type(4)));

// ---------------------------------------------------------------------------
// Weight prep: 64x64 LDS transpose, then emit bf16 weights in MFMA-FRAGMENT
// order: 16B chunk for (col c, k-chunk kc) lives at chunk index
// ((c>>4)*32 + kc)*16 + (c&15). A wave's B-frag load is then base + lane*16
// (fully coalesced). 57 blocks.
// ---------------------------------------------------------------------------
__global__ __launch_bounds__(256) void prep_weights(
    const float* __restrict__ vproj_w, const float* __restrict__ off_w,
    const float* __restrict__ attn_w, const float* __restrict__ out_w,
    const float* __restrict__ off_b, const float* __restrict__ attn_b,
    bf16* __restrict__ bt_v, bf16* __restrict__ bt_oa, bf16* __restrict__ bt_out,
    float* __restrict__ bias_oa)
{
    const int blk = blockIdx.x;
    const int t = threadIdx.x;
    if (blk == 56) {
        bias_oa[t] = off_b[t];
        if (t < 128) bias_oa[256 + t] = attn_b[t];
        return;
    }
    const float* W; bf16* BT; int N, tn, tk, cbase;
    if (blk < 16)      { W = vproj_w; BT = bt_v;   N = 256; tk = blk >> 2;        tn = blk & 3;        cbase = 0; }
    else if (blk < 32) { W = off_w;   BT = bt_oa;  N = 256; tk = (blk - 16) >> 2; tn = (blk - 16) & 3; cbase = 0; }
    else if (blk < 40) { W = attn_w;  BT = bt_oa;  N = 128; tk = (blk - 32) >> 1; tn = (blk - 32) & 1; cbase = 256; }
    else               { W = out_w;   BT = bt_out; N = 256; tk = (blk - 40) >> 2; tn = (blk - 40) & 3; cbase = 0; }
    const int k0 = tk * 64, n0 = tn * 64;

    __shared__ float sT[64][65];
    const int r = t >> 2;             // 0..63
    const int cs = (t & 3) * 16;      // k segment
    const float* src = W + (size_t)(k0 + r) * N + n0 + cs;
#pragma unroll
    for (int i = 0; i < 4; ++i) {
        float4 a = *(const float4*)(src + i * 4);
        sT[r][cs + i * 4 + 0] = a.x; sT[r][cs + i * 4 + 1] = a.y;
        sT[r][cs + i * 4 + 2] = a.z; sT[r][cs + i * 4 + 3] = a.w;
    }
    __syncthreads();
    // thread emits col c = cbase+n0+r, k range [k0+cs, k0+cs+16) = chunks kc0, kc0+1
    const int c = cbase + n0 + r;
    const int ng = c >> 4, cl = c & 15;
    const int kc0 = (k0 + cs) >> 3;
    bf16x8 o0, o1;
#pragma unroll
    for (int i = 0; i < 8; ++i) o0[i] = (bf16)sT[cs + i][r];
#pragma unroll
    for (int i = 0; i < 8; ++i) o1[i] = (bf16)sT[cs + 8 + i][r];
    *(bf16x8*)(BT + (size_t)(((ng * 32 + kc0) * 16 + cl) * 8)) = o0;
    *(bf16x8*)(BT + (size_t)(((ng * 32 + kc0 + 1) * 16 + cl) * 8)) = o1;
}

// ---------------------------------------------------------------------------
// GEMM body, tile 64 rows x 128 cols, K=256, 4 waves.
//  - A staged coalesced (1 KB/wave-instr) into 32 KB chunk-swizzled LDS.
//  - B fragments loaded coalesced from fragment-ordered global (16 instrs,
//    1 KB each), held in 64 VGPRs.
//  - Per mtile: 8 conflict-free ds_read_b128 + 16 MFMA.
// ---------------------------------------------------------------------------
template <typename AT, typename OutT>
__device__ __forceinline__ void gemm_body(
    const AT* __restrict__ A, const bf16* __restrict__ BF,
    const float* __restrict__ bias, OutT* __restrict__ C,
    int N, int n0, int m0, int tid)
{
    __shared__ bf16 sA[64 * 256];   // 32 KB

    const int wave = tid >> 6;
    const int lane = tid & 63;
    const int l15  = lane & 15;
    const int quad = lane >> 4;

    // ---- stage A (coalesced) ----
    if constexpr (std::is_same_v<AT, float>) {
#pragma unroll
        for (int it = 0; it < 16; ++it) {
            const int R = wave * 16 + it;
            float4 f = *(const float4*)(A + (size_t)(m0 + R) * 256 + lane * 4);
            bf16x4 h = {(bf16)f.x, (bf16)f.y, (bf16)f.z, (bf16)f.w};
            const int ch = lane >> 1, half = lane & 1;
            *(bf16x4*)(sA + R * 256 + ((ch ^ (R & 7)) << 3) + (half << 2)) = h;
        }
    } else {
#pragma unroll
        for (int it = 0; it < 8; ++it) {
            const int R = wave * 16 + it * 2 + (lane >> 5);
            const int ch = lane & 31;
            bf16x8 h = *(const bf16x8*)(A + (size_t)(m0 + R) * 256 + ch * 8);
            *(bf16x8*)(sA + R * 256 + ((ch ^ (R & 7)) << 3)) = h;
        }
    }

    // ---- B fragments (coalesced, fragment-ordered buffer) ----
    const int ng0 = (n0 >> 4) + wave * 2;
    bf16x8 bfr[2][8];
#pragma unroll
    for (int nt = 0; nt < 2; ++nt) {
        const bf16* bp = BF + (size_t)(ng0 + nt) * 4096 + lane * 8;
#pragma unroll
        for (int ki = 0; ki < 8; ++ki)
            bfr[nt][ki] = *(const bf16x8*)(bp + ki * 512);
    }

    __syncthreads();

    f32x4 acc[4][2] = {};

#pragma unroll
    for (int mt = 0; mt < 4; ++mt) {
        const int R = mt * 16 + l15;
        const bf16* ab = sA + R * 256;
        const int sw = R & 7;
        bf16x8 afr[8];
#pragma unroll
        for (int ki = 0; ki < 8; ++ki)
            afr[ki] = *(const bf16x8*)(ab + (((ki * 4 + quad) ^ sw) << 3));
#pragma unroll
        for (int ki = 0; ki < 8; ++ki) {
#pragma unroll
            for (int nt = 0; nt < 2; ++nt)
                acc[mt][nt] = __builtin_amdgcn_mfma_f32_16x16x32_bf16(
                    afr[ki], bfr[nt][ki], acc[mt][nt], 0, 0, 0);
        }
    }

#pragma unroll
    for (int mt = 0; mt < 4; ++mt) {
#pragma unroll
        for (int nt = 0; nt < 2; ++nt) {
            const int col = n0 + wave * 32 + nt * 16 + l15;
            const float bv = bias[col];
#pragma unroll
            for (int r = 0; r < 4; ++r) {
                const int rr = m0 + mt * 16 + (quad << 2) + r;
                float val = acc[mt][nt][r] + bv;
                if constexpr (std::is_same_v<OutT, float>)
                    C[(uint32_t)(rr * N + col)] = val;
                else
                    C[(uint32_t)(rr * N + col)] = (bf16)val;
            }
        }
    }
}

// Front GEMMs fused: 1700 blocks = 340 m-stripes x 5 n-blocks.
// nb 0,1 -> value@vproj (N=256); nb 2,3,4 -> query@[off|attn] (N=384).
__global__ __launch_bounds__(256) void gemm_front(
    const float* __restrict__ value, const float* __restrict__ query,
    const bf16* __restrict__ bt_v, const bf16* __restrict__ bt_oa,
    const float* __restrict__ bias_v, const float* __restrict__ bias_oa,
    bf16* __restrict__ v_bf, bf16* __restrict__ oa_bf)
{
    const int bx = blockIdx.x;
    const int m = bx / 5, nb = bx % 5;
    if (nb < 2)
        gemm_body<float, bf16>(value, bt_v, bias_v, v_bf, 256, nb * 128, m * 64, threadIdx.x);
    else
        gemm_body<float, bf16>(query, bt_oa, bias_oa, oa_bf, 384, (nb - 2) * 128, m * 64, threadIdx.x);
}

// Back GEMM: 680 blocks = 340 m x 2 n.
__global__ __launch_bounds__(256) void gemm_back(
    const bf16* __restrict__ pre, const bf16* __restrict__ bt_out,
    const float* __restrict__ out_b, float* __restrict__ out)
{
    const int bx = blockIdx.x;
    gemm_body<bf16, float>(pre, bt_out, out_b, out, 256, (bx & 1) * 128,
                           (bx >> 1) * 64, threadIdx.x);
}

// ---------------------------------------------------------------------------
// Fused softmax + multi-scale bilinear sampling (unchanged from round 5).
// ---------------------------------------------------------------------------
__global__ __launch_bounds__(256) void msda_sample(
    const bf16* __restrict__ v,        // [BS][LEN][256]
    const float* __restrict__ ref_pts, // [BS][LEN][4][2]
    const bf16* __restrict__ oa,       // [BS][LEN][384]
    bf16* __restrict__ pre)            // [BS][LEN][256]
{
    const int ib = blockIdx.x;
    const int b  = (ib & 7) >> 1;
    const int qg = ((ib >> 3) << 1) + (ib & 1);
    const int q0 = qg * 4;
    const int tid = threadIdx.x;

    __shared__ float  s_ref[32];
    __shared__ float  s_wn[512];
    __shared__ float4 s_tw[544];    // [32 (q,h)][16 pt] stride 17
    __shared__ int4   s_to[544];

    const uint32_t rowbase = (uint32_t)(b * LEN + q0);

    if (tid < 32) {
        s_ref[tid] = ref_pts[rowbase * 8 + tid];
        const int qi = tid >> 3, h = tid & 7;
        const bf16* ap = oa + (rowbase + qi) * 384 + 256 + h * 16;
        bf16x8 l0 = *(const bf16x8*)ap;
        bf16x8 l1 = *(const bf16x8*)(ap + 8);
        float lg[16];
#pragma unroll
        for (int i = 0; i < 8; ++i) { lg[i] = (float)l0[i]; lg[8 + i] = (float)l1[i]; }
        float m = -1e30f;
#pragma unroll
        for (int i = 0; i < 16; ++i) m = fmaxf(m, lg[i]);
        float s = 0.f;
#pragma unroll
        for (int i = 0; i < 16; ++i) { lg[i] = __expf(lg[i] - m); s += lg[i]; }
        const float inv = 1.f / s;
#pragma unroll
        for (int i = 0; i < 16; ++i) s_wn[qi * 128 + h * 16 + i] = lg[i] * inv;
    }
    __syncthreads();

#pragma unroll
    for (int it = 0; it < 2; ++it) {
        const int item = tid + it * 256;
        const int g  = item >> 4;
        const int qi = item >> 7;
        const int h  = (item >> 4) & 7;
        const int pt = item & 15;
        const int l  = pt >> 2;
        const int iw = 64 >> l;
        const int st = (l == 0) ? 0 : ((l == 1) ? 4096 : ((l == 2) ? 5120 : 5376));
        const float fiw = (float)iw;

        bf16x2 ob = *(const bf16x2*)(oa + (rowbase + qi) * 384 + (h * 16 + pt) * 2);
        const float x = s_ref[qi * 8 + l * 2 + 0] * fiw - 0.5f + (float)ob[0];
        const float y = s_ref[qi * 8 + l * 2 + 1] * fiw - 0.5f + (float)ob[1];
        const float x0f = floorf(x), y0f = floorf(y);
        const int x0 = (int)x0f, y0 = (int)y0f;
        const int x1 = x0 + 1, y1 = y0 + 1;
        const float fx = x - x0f, fy = y - y0f;
        const float wa = s_wn[qi * 128 + h * 16 + pt];
        const float w00 = (1.f - fx) * (1.f - fy) * wa;
        const float w10 = (1.f - fx) * fy * wa;
        const float w01 = fx * (1.f - fy) * wa;
        const float w11 = fx * fy * wa;
        const bool xi0 = (x0 >= 0) & (x0 < iw);
        const bool xi1 = (x1 >= 0) & (x1 < iw);
        const bool yi0 = (y0 >= 0) & (y0 < iw);
        const bool yi1 = (y1 >= 0) & (y1 < iw);
        const int xc0 = min(max(x0, 0), iw - 1), xc1 = min(max(x1, 0), iw - 1);
        const int yc0 = min(max(y0, 0), iw - 1), yc1 = min(max(y1, 0), iw - 1);
        const int hb = h * 64;
        s_tw[g * 17 + pt] = make_float4((xi0 & yi0) ? w00 : 0.f, (xi0 & yi1) ? w10 : 0.f,
                                        (xi1 & yi0) ? w01 : 0.f, (xi1 & yi1) ? w11 : 0.f);
        s_to[g * 17 + pt] = make_int4(((st + yc0 * iw + xc0) << 9) + hb,
                                      ((st + yc1 * iw + xc0) << 9) + hb,
                                      ((st + yc0 * iw + xc1) << 9) + hb,
                                      ((st + yc1 * iw + xc1) << 9) + hb);
    }
    __syncthreads();

    const int qi = tid >> 6;
    const int u  = tid & 63;
    const int h  = u >> 3;
    const int c8 = u & 7;
    const char* vbc = (const char*)(v + (uint32_t)b * (LEN * 256));
    const uint32_t lb = (uint32_t)(c8 * 8);
    const int base = (qi * 8 + h) * 17;

    float a0 = 0.f, a1 = 0.f, a2 = 0.f, a3 = 0.f;
#pragma unroll
    for (int pt = 0; pt < 16; ++pt) {
        const float4 w4 = s_tw[base + pt];
        const int4   o4 = s_to[base + pt];
#define TAP(OFF, W) { \
        uint2 d = *(const uint2*)(vbc + ((uint32_t)(OFF) + lb)); \
        a0 = fmaf(__uint_as_float(d.x << 16),          (W), a0); \
        a1 = fmaf(__uint_as_float(d.x & 0xffff0000u),  (W), a1); \
        a2 = fmaf(__uint_as_float(d.y << 16),          (W), a2); \
        a3 = fmaf(__uint_as_float(d.y & 0xffff0000u),  (W), a3); }
        TAP(o4.x, w4.x)
        TAP(o4.y, w4.y)
        TAP(o4.z, w4.z)
        TAP(o4.w, w4.w)
#undef TAP
    }

    bf16x4 o = {(bf16)a0, (bf16)a1, (bf16)a2, (bf16)a3};
    *(bf16x4*)(pre + (rowbase + qi) * 256 + h * 32 + c8 * 4) = o;
}

// ---------------------------------------------------------------------------
// Launch: 4 dispatches
// ---------------------------------------------------------------------------
extern "C" void kernel_launch(void* const* d_in, const int* in_sizes, int n_in,
                              void* d_out, int out_size, void* d_ws, size_t ws_size,
                              hipStream_t stream) {
    const float* query   = (const float*)d_in[0];
    const float* ref_pts = (const float*)d_in[1];
    const float* value   = (const float*)d_in[2];
    const float* vproj_w = (const float*)d_in[5];
    const float* vproj_b = (const float*)d_in[6];
    const float* off_w   = (const float*)d_in[7];
    const float* off_b   = (const float*)d_in[8];
    const float* attn_w  = (const float*)d_in[9];
    const float* attn_b  = (const float*)d_in[10];
    const float* out_w   = (const float*)d_in[11];
    const float* out_b   = (const float*)d_in[12];
    float* out = (float*)d_out;

    bf16* ws = (bf16*)d_ws;
    bf16* v_bf    = ws;                                // ROWS*256
    bf16* oa_bf   = v_bf   + (size_t)ROWS * 256;       // ROWS*384
    bf16* pre_bf  = oa_bf  + (size_t)ROWS * 384;       // ROWS*256
    bf16* bt_v    = pre_bf + (size_t)ROWS * 256;       // 256*256 (frag order)
    bf16* bt_oa   = bt_v   + 256 * 256;                // 384*256 (frag order)
    bf16* bt_out  = bt_oa  + 384 * 256;                // 256*256 (frag order)
    float* bias_oa = (float*)(bt_out + 256 * 256);     // 384 f32

    dim3 blk(256);

    prep_weights<<<dim3(57), blk, 0, stream>>>(vproj_w, off_w, attn_w, out_w,
                                               off_b, attn_b, bt_v, bt_oa, bt_out, bias_oa);

    gemm_front<<<dim3(1700), blk, 0, stream>>>(value, query, bt_v, bt_oa,
                                               vproj_b, bias_oa, v_bf, oa_bf);

    msda_sample<<<dim3(5440), blk, 0, stream>>>(v_bf, ref_pts, oa_bf, pre_bf);

    gemm_back<<<dim3(680), blk, 0, stream>>>(pre_bf, bt_out, out_b, out);
}

// Round 7
// 166.408 us; speedup vs baseline: 1.3794x; 1.0568x over previous
//
#include <hip/hip_runtime.h>
#include <hip/hip_bf16.h>
#include <stdint.h>
#include <type_traits>

#define BS 4
#define LEN 5440
#define ROWS (BS * LEN)     // 21760 = 340 * 64

typedef __bf16 bf16;
typedef _Float16 f16;
typedef __bf16 bf16x2 __attribute__((ext_vector_type(2)));
typedef __bf16 bf16x4 __attribute__((ext_vector_type(4)));
typedef __bf16 bf16x8 __attribute__((ext_vector_type(8)));
typedef _Float16 f16x8 __attribute__((ext_vector_type(8)));
typedef float f32x4 __attribute__((ext_vector_type(4)));

// ---------------------------------------------------------------------------
// Weight prep: 64x64 LDS transpose -> bf16 weights in MFMA-fragment order:
// chunk for (col c, k-chunk kc) at ((c>>4)*32 + kc)*16 + (c&15). 57 blocks.
// ---------------------------------------------------------------------------
__global__ __launch_bounds__(256) void prep_weights(
    const float* __restrict__ vproj_w, const float* __restrict__ off_w,
    const float* __restrict__ attn_w, const float* __restrict__ out_w,
    const float* __restrict__ off_b, const float* __restrict__ attn_b,
    bf16* __restrict__ bt_v, bf16* __restrict__ bt_oa, bf16* __restrict__ bt_out,
    float* __restrict__ bias_oa)
{
    const int blk = blockIdx.x;
    const int t = threadIdx.x;
    if (blk == 56) {
        bias_oa[t] = off_b[t];
        if (t < 128) bias_oa[256 + t] = attn_b[t];
        return;
    }
    const float* W; bf16* BT; int N, tn, tk, cbase;
    if (blk < 16)      { W = vproj_w; BT = bt_v;   N = 256; tk = blk >> 2;        tn = blk & 3;        cbase = 0; }
    else if (blk < 32) { W = off_w;   BT = bt_oa;  N = 256; tk = (blk - 16) >> 2; tn = (blk - 16) & 3; cbase = 0; }
    else if (blk < 40) { W = attn_w;  BT = bt_oa;  N = 128; tk = (blk - 32) >> 1; tn = (blk - 32) & 1; cbase = 256; }
    else               { W = out_w;   BT = bt_out; N = 256; tk = (blk - 40) >> 2; tn = (blk - 40) & 3; cbase = 0; }
    const int k0 = tk * 64, n0 = tn * 64;

    __shared__ float sT[64][65];
    const int r = t >> 2;
    const int cs = (t & 3) * 16;
    const float* src = W + (size_t)(k0 + r) * N + n0 + cs;
#pragma unroll
    for (int i = 0; i < 4; ++i) {
        float4 a = *(const float4*)(src + i * 4);
        sT[r][cs + i * 4 + 0] = a.x; sT[r][cs + i * 4 + 1] = a.y;
        sT[r][cs + i * 4 + 2] = a.z; sT[r][cs + i * 4 + 3] = a.w;
    }
    __syncthreads();
    const int c = cbase + n0 + r;
    const int ng = c >> 4, cl = c & 15;
    const int kc0 = (k0 + cs) >> 3;
    bf16x8 o0, o1;
#pragma unroll
    for (int i = 0; i < 8; ++i) o0[i] = (bf16)sT[cs + i][r];
#pragma unroll
    for (int i = 0; i < 8; ++i) o1[i] = (bf16)sT[cs + 8 + i][r];
    *(bf16x8*)(BT + (size_t)(((ng * 32 + kc0) * 16 + cl) * 8)) = o0;
    *(bf16x8*)(BT + (size_t)(((ng * 32 + kc0 + 1) * 16 + cl) * 8)) = o1;
}

// ---------------------------------------------------------------------------
// GEMM body (unchanged from round 6): tile 64x128, coalesced A->LDS staging,
// fragment-ordered coalesced B->regs, conflict-free ds_read + MFMA.
// ---------------------------------------------------------------------------
template <typename AT, typename OutT>
__device__ __forceinline__ void gemm_body(
    const AT* __restrict__ A, const bf16* __restrict__ BF,
    const float* __restrict__ bias, OutT* __restrict__ C,
    int N, int n0, int m0, int tid)
{
    __shared__ bf16 sA[64 * 256];   // 32 KB

    const int wave = tid >> 6;
    const int lane = tid & 63;
    const int l15  = lane & 15;
    const int quad = lane >> 4;

    if constexpr (std::is_same_v<AT, float>) {
#pragma unroll
        for (int it = 0; it < 16; ++it) {
            const int R = wave * 16 + it;
            float4 f = *(const float4*)(A + (size_t)(m0 + R) * 256 + lane * 4);
            bf16x4 h = {(bf16)f.x, (bf16)f.y, (bf16)f.z, (bf16)f.w};
            const int ch = lane >> 1, half = lane & 1;
            *(bf16x4*)(sA + R * 256 + ((ch ^ (R & 7)) << 3) + (half << 2)) = h;
        }
    } else {
#pragma unroll
        for (int it = 0; it < 8; ++it) {
            const int R = wave * 16 + it * 2 + (lane >> 5);
            const int ch = lane & 31;
            bf16x8 h = *(const bf16x8*)(A + (size_t)(m0 + R) * 256 + ch * 8);
            *(bf16x8*)(sA + R * 256 + ((ch ^ (R & 7)) << 3)) = h;
        }
    }

    const int ng0 = (n0 >> 4) + wave * 2;
    bf16x8 bfr[2][8];
#pragma unroll
    for (int nt = 0; nt < 2; ++nt) {
        const bf16* bp = BF + (size_t)(ng0 + nt) * 4096 + lane * 8;
#pragma unroll
        for (int ki = 0; ki < 8; ++ki)
            bfr[nt][ki] = *(const bf16x8*)(bp + ki * 512);
    }

    __syncthreads();

    f32x4 acc[4][2] = {};

#pragma unroll
    for (int mt = 0; mt < 4; ++mt) {
        const int R = mt * 16 + l15;
        const bf16* ab = sA + R * 256;
        const int sw = R & 7;
        bf16x8 afr[8];
#pragma unroll
        for (int ki = 0; ki < 8; ++ki)
            afr[ki] = *(const bf16x8*)(ab + (((ki * 4 + quad) ^ sw) << 3));
#pragma unroll
        for (int ki = 0; ki < 8; ++ki) {
#pragma unroll
            for (int nt = 0; nt < 2; ++nt)
                acc[mt][nt] = __builtin_amdgcn_mfma_f32_16x16x32_bf16(
                    afr[ki], bfr[nt][ki], acc[mt][nt], 0, 0, 0);
        }
    }

#pragma unroll
    for (int mt = 0; mt < 4; ++mt) {
#pragma unroll
        for (int nt = 0; nt < 2; ++nt) {
            const int col = n0 + wave * 32 + nt * 16 + l15;
            const float bv = bias[col];
#pragma unroll
            for (int r = 0; r < 4; ++r) {
                const int rr = m0 + mt * 16 + (quad << 2) + r;
                C[(uint32_t)(rr * N + col)] = static_cast<OutT>(acc[mt][nt][r] + bv);
            }
        }
    }
}

// Front GEMMs fused: 1700 blocks = 340 m-stripes x 5 n-blocks.
// nb 0,1 -> value@vproj -> f16 v ; nb 2,3,4 -> query@[off|attn] -> bf16 oa.
__global__ __launch_bounds__(256) void gemm_front(
    const float* __restrict__ value, const float* __restrict__ query,
    const bf16* __restrict__ bt_v, const bf16* __restrict__ bt_oa,
    const float* __restrict__ bias_v, const float* __restrict__ bias_oa,
    f16* __restrict__ v_h, bf16* __restrict__ oa_bf)
{
    const int bx = blockIdx.x;
    const int m = bx / 5, nb = bx % 5;
    if (nb < 2)
        gemm_body<float, f16>(value, bt_v, bias_v, v_h, 256, nb * 128, m * 64, threadIdx.x);
    else
        gemm_body<float, bf16>(query, bt_oa, bias_oa, oa_bf, 384, (nb - 2) * 128, m * 64, threadIdx.x);
}

__global__ __launch_bounds__(256) void gemm_back(
    const bf16* __restrict__ pre, const bf16* __restrict__ bt_out,
    const float* __restrict__ out_b, float* __restrict__ out)
{
    const int bx = blockIdx.x;
    gemm_body<bf16, float>(pre, bt_out, out_b, out, 256, (bx & 1) * 128,
                           (bx >> 1) * 64, threadIdx.x);
}

// ---------------------------------------------------------------------------
// Fused softmax + sampling, 8 queries/block, 16B gathers, v_fma_mix FMAs.
// Phase 0: softmax once per (q,h). Phase 1: tap weights/offsets -> LDS.
// Phase 2: wave = 16 (q,h) groups (2 queries); lane = (group, 16B chunk).
// ---------------------------------------------------------------------------
__global__ __launch_bounds__(256) void msda_sample(
    const f16* __restrict__ v,         // [BS][LEN][256] f16
    const float* __restrict__ ref_pts, // [BS][LEN][4][2]
    const bf16* __restrict__ oa,       // [BS][LEN][384]
    bf16* __restrict__ pre)            // [BS][LEN][256]
{
    const int ib = blockIdx.x;          // [0, 2720)
    const int b  = (ib & 7) >> 1;       // batch per XCD-pair
    const int qg = ((ib >> 3) << 1) + (ib & 1);   // [0, 680)
    const int q0 = qg * 8;
    const int tid = threadIdx.x;

    __shared__ float  s_ref[64];        // [8 q][8]
    __shared__ float  s_wn[1024];       // [8 q][128]
    __shared__ float4 s_tw[1088];       // [64 (q,h)][16 pt] stride 17
    __shared__ int4   s_to[1088];

    const uint32_t rowbase = (uint32_t)(b * LEN + q0);

    // Phase 0: ref points + softmax, one (q,h) per thread (tid<64)
    if (tid < 64) {
        s_ref[tid] = ref_pts[rowbase * 8 + tid];
        const int qi = tid >> 3, h = tid & 7;
        const bf16* ap = oa + (rowbase + qi) * 384 + 256 + h * 16;
        bf16x8 l0 = *(const bf16x8*)ap;
        bf16x8 l1 = *(const bf16x8*)(ap + 8);
        float lg[16];
#pragma unroll
        for (int i = 0; i < 8; ++i) { lg[i] = (float)l0[i]; lg[8 + i] = (float)l1[i]; }
        float m = -1e30f;
#pragma unroll
        for (int i = 0; i < 16; ++i) m = fmaxf(m, lg[i]);
        float s = 0.f;
#pragma unroll
        for (int i = 0; i < 16; ++i) { lg[i] = __expf(lg[i] - m); s += lg[i]; }
        const float inv = 1.f / s;
#pragma unroll
        for (int i = 0; i < 16; ++i) s_wn[qi * 128 + h * 16 + i] = lg[i] * inv;
    }
    __syncthreads();

    // Phase 1: 1024 items (q,h,pt), 4 per thread
#pragma unroll
    for (int it = 0; it < 4; ++it) {
        const int item = tid + it * 256;
        const int g  = item >> 4;         // (qi*8 + h), 0..63
        const int qi = item >> 7;
        const int h  = (item >> 4) & 7;
        const int pt = item & 15;
        const int l  = pt >> 2;
        const int iw = 64 >> l;
        const int st = (l == 0) ? 0 : ((l == 1) ? 4096 : ((l == 2) ? 5120 : 5376));
        const float fiw = (float)iw;

        bf16x2 ob = *(const bf16x2*)(oa + (rowbase + qi) * 384 + (h * 16 + pt) * 2);
        const float x = s_ref[qi * 8 + l * 2 + 0] * fiw - 0.5f + (float)ob[0];
        const float y = s_ref[qi * 8 + l * 2 + 1] * fiw - 0.5f + (float)ob[1];
        const float x0f = floorf(x), y0f = floorf(y);
        const int x0 = (int)x0f, y0 = (int)y0f;
        const int x1 = x0 + 1, y1 = y0 + 1;
        const float fx = x - x0f, fy = y - y0f;
        const float wa = s_wn[qi * 128 + h * 16 + pt];
        const float w00 = (1.f - fx) * (1.f - fy) * wa;
        const float w10 = (1.f - fx) * fy * wa;
        const float w01 = fx * (1.f - fy) * wa;
        const float w11 = fx * fy * wa;
        const bool xi0 = (x0 >= 0) & (x0 < iw);
        const bool xi1 = (x1 >= 0) & (x1 < iw);
        const bool yi0 = (y0 >= 0) & (y0 < iw);
        const bool yi1 = (y1 >= 0) & (y1 < iw);
        const int xc0 = min(max(x0, 0), iw - 1), xc1 = min(max(x1, 0), iw - 1);
        const int yc0 = min(max(y0, 0), iw - 1), yc1 = min(max(y1, 0), iw - 1);
        const int hb = h * 64;
        s_tw[g * 17 + pt] = make_float4((xi0 & yi0) ? w00 : 0.f, (xi0 & yi1) ? w10 : 0.f,
                                        (xi1 & yi0) ? w01 : 0.f, (xi1 & yi1) ? w11 : 0.f);
        s_to[g * 17 + pt] = make_int4(((st + yc0 * iw + xc0) << 9) + hb,
                                      ((st + yc1 * iw + xc0) << 9) + hb,
                                      ((st + yc0 * iw + xc1) << 9) + hb,
                                      ((st + yc1 * iw + xc1) << 9) + hb);
    }
    __syncthreads();

    // Phase 2: wave w -> groups w*16..+15 (queries w*2, w*2+1);
    // lane: gl = lane>>2 (group), c4 = lane&3 (16B chunk = 8 channels).
    const int wave = tid >> 6;
    const int lane = tid & 63;
    const int gl = lane >> 2, c4 = lane & 3;
    const int g = wave * 16 + gl;
    const int qi = g >> 3, h = g & 7;
    const char* vbc = (const char*)v + (uint32_t)b * (LEN * 512);
    const uint32_t lb = (uint32_t)(c4 * 16);
    const int base = g * 17;

    float acc[8] = {};
#pragma unroll
    for (int pt = 0; pt < 16; ++pt) {
        const float4 w4 = s_tw[base + pt];
        const int4   o4 = s_to[base + pt];
#define TAP(OFF, W) { \
        f16x8 d = *(const f16x8*)(vbc + ((uint32_t)(OFF) + lb)); \
        _Pragma("unroll") \
        for (int j = 0; j < 8; ++j) acc[j] = fmaf((float)d[j], (W), acc[j]); }
        TAP(o4.x, w4.x)
        TAP(o4.y, w4.y)
        TAP(o4.z, w4.z)
        TAP(o4.w, w4.w)
#undef TAP
    }

    bf16x8 o;
#pragma unroll
    for (int j = 0; j < 8; ++j) o[j] = (bf16)acc[j];
    *(bf16x8*)(pre + (rowbase + qi) * 256 + h * 32 + c4 * 8) = o;
}

// ---------------------------------------------------------------------------
// Launch: 4 dispatches
// ---------------------------------------------------------------------------
extern "C" void kernel_launch(void* const* d_in, const int* in_sizes, int n_in,
                              void* d_out, int out_size, void* d_ws, size_t ws_size,
                              hipStream_t stream) {
    const float* query   = (const float*)d_in[0];
    const float* ref_pts = (const float*)d_in[1];
    const float* value   = (const float*)d_in[2];
    const float* vproj_w = (const float*)d_in[5];
    const float* vproj_b = (const float*)d_in[6];
    const float* off_w   = (const float*)d_in[7];
    const float* off_b   = (const float*)d_in[8];
    const float* attn_w  = (const float*)d_in[9];
    const float* attn_b  = (const float*)d_in[10];
    const float* out_w   = (const float*)d_in[11];
    const float* out_b   = (const float*)d_in[12];
    float* out = (float*)d_out;

    bf16* ws = (bf16*)d_ws;
    f16*  v_h     = (f16*)ws;                          // ROWS*256 (f16)
    bf16* oa_bf   = ws     + (size_t)ROWS * 256;       // ROWS*384
    bf16* pre_bf  = oa_bf  + (size_t)ROWS * 384;       // ROWS*256
    bf16* bt_v    = pre_bf + (size_t)ROWS * 256;       // 256*256 (frag order)
    bf16* bt_oa   = bt_v   + 256 * 256;                // 384*256 (frag order)
    bf16* bt_out  = bt_oa  + 384 * 256;                // 256*256 (frag order)
    float* bias_oa = (float*)(bt_out + 256 * 256);     // 384 f32

    dim3 blk(256);

    prep_weights<<<dim3(57), blk, 0, stream>>>(vproj_w, off_w, attn_w, out_w,
                                               off_b, attn_b, bt_v, bt_oa, bt_out, bias_oa);

    gemm_front<<<dim3(1700), blk, 0, stream>>>(value, query, bt_v, bt_oa,
                                               vproj_b, bias_oa, v_h, oa_bf);

    msda_sample<<<dim3(2720), blk, 0, stream>>>(v_h, ref_pts, oa_bf, pre_bf);

    gemm_back<<<dim3(680), blk, 0, stream>>>(pre_bf, bt_out, out_b, out);
}